// Round 9
// baseline (474.399 us; speedup 1.0000x reference)
//
#include <hip/hip_runtime.h>

#define DEVINL static __device__ __forceinline__

typedef __attribute__((ext_vector_type(4)))  float f32x4;
typedef __attribute__((ext_vector_type(16))) float f32x16;
typedef __attribute__((ext_vector_type(4)))  float float4_t;
typedef __attribute__((ext_vector_type(8)))  short short8;
typedef __attribute__((ext_vector_type(4)))  short short4v;
typedef __attribute__((ext_vector_type(4)))  int   int4v;

DEVINL unsigned short f2bf(float f){
  union { float f; unsigned int u; } x; x.f = f;
  return (unsigned short)((x.u + 0x7fffu + ((x.u >> 16) & 1u)) >> 16);
}
DEVINL float bf2f(unsigned short h){
  union { unsigned int u; float f; } x; x.u = ((unsigned int)h) << 16;
  return x.f;
}
DEVINL f32x4 zero4(){ f32x4 z; z[0]=0.f; z[1]=0.f; z[2]=0.f; z[3]=0.f; return z; }
DEVINL f32x16 zero16(){ f32x16 z;
#pragma unroll
  for (int e=0;e<16;++e) z[e]=0.f;
  return z; }

// Rule-18-correct barrier: drain LDS ops only; sched_barrier fences stop hipcc
// from moving LDS ops / MFMAs across the inline-asm waitcnt.
#define BARX() do{ \
  __builtin_amdgcn_sched_barrier(0); \
  asm volatile("s_waitcnt lgkmcnt(0)" ::: "memory"); \
  __builtin_amdgcn_sched_barrier(0); \
  __builtin_amdgcn_s_barrier(); \
  __builtin_amdgcn_sched_barrier(0); \
}while(0)

// async global->LDS, 16B per lane
#define GLL16(gp, lp) __builtin_amdgcn_global_load_lds( \
    (const __attribute__((address_space(1))) void*)(gp), \
    (__attribute__((address_space(3))) void*)(lp), 16, 0, 0)

// ---------------- prep: f32 -> bf16 casts ----------------
__global__ __launch_bounds__(256) void cast_f32_bf16(const float* __restrict__ src,
                                                     unsigned short* __restrict__ dst, int n8){
  int i = blockIdx.x * 256 + threadIdx.x;
  if (i >= n8) return;
  const float4_t* s = (const float4_t*)src;
  float4_t a = s[2*i], b = s[2*i+1];
  short8 o;
  o[0]=(short)f2bf(a[0]); o[1]=(short)f2bf(a[1]); o[2]=(short)f2bf(a[2]); o[3]=(short)f2bf(a[3]);
  o[4]=(short)f2bf(b[0]); o[5]=(short)f2bf(b[1]); o[6]=(short)f2bf(b[2]); o[7]=(short)f2bf(b[3]);
  *(short8*)(dst + (size_t)i*8) = o;
}

// EmT[g][h] = softmax(ent,axis=-1)[h][g] * (log2(e)/sqrt(D)); rows g=16..31 zero-padded.
__global__ __launch_bounds__(256) void prep_em(const float* __restrict__ ent,
                                               unsigned short* __restrict__ EmT){
  int t = threadIdx.x;
  if (t < 16){
    float v[16]; float mx = -3.0e38f;
#pragma unroll
    for (int j=0;j<16;++j){ v[j] = ent[t*16 + j]; mx = fmaxf(mx, v[j]); }
    float s = 0.f;
#pragma unroll
    for (int j=0;j<16;++j){ v[j] = __expf(v[j]-mx); s += v[j]; }
    float inv = (1.f/s) * 0.125f * 1.4426950408889634f;
#pragma unroll
    for (int j=0;j<16;++j) EmT[j*16 + t] = f2bf(v[j]*inv);
  }
  EmT[256 + t] = 0; // zero pad rows 16..31
}

// ---------------- mask [B][1][S][S] int32 -> bit-packed [B][S][S/32] ----------------
__global__ __launch_bounds__(256) void prep_maskbits(const int* __restrict__ mask,
                                                     unsigned* __restrict__ mb){
  int id = blockIdx.x * 256 + threadIdx.x;   // 262144 words
  const int* src = mask + (size_t)id * 32;
  unsigned word = 0u;
#pragma unroll
  for (int c=0;c<8;++c){
    int4v v = *(const int4v*)(src + c*4);
    word |= (unsigned)(v[0]!=0) << (c*4)
          | (unsigned)(v[1]!=0) << (c*4+1)
          | (unsigned)(v[2]!=0) << (c*4+2)
          | (unsigned)(v[3]!=0) << (c*4+3);
  }
  mb[id] = word;
}

// ---------------- GEMM: C = A(bf16,[M][1024]) * W^T(bf16,[N][K]) + bias ----------------
template<int MODE>
__global__ __launch_bounds__(256) void gemm_bt(const unsigned short* __restrict__ A,
                                               const unsigned short* __restrict__ W4,
                                               const float* __restrict__ bias0,
                                               const float* __restrict__ bias1,
                                               const float* __restrict__ bias2,
                                               void* __restrict__ outp){
  __shared__ __align__(16) unsigned short As[4096];
  __shared__ __align__(16) unsigned short Bs[4096];
  const int tid = threadIdx.x;
  const int w = tid >> 6, ln = tid & 63;
  const int wm = w >> 1, wn = w & 1;
  const int lq = ln & 15, lg = ln >> 4;
  const int m0 = blockIdx.y * 128, n0 = blockIdx.x * 128;
  const int z = blockIdx.z;
  const unsigned short* Bt = W4 + (size_t)z * 1048576;
  const float* bias = (z == 0) ? bias0 : ((z == 1) ? bias1 : bias2);

  const unsigned short* Ag = A  + (size_t)(m0 + (tid >> 2)) * 1024 + (tid & 3) * 8;
  const unsigned short* Bg = Bt + (size_t)(n0 + (tid >> 2)) * 1024 + (tid & 3) * 8;
  unsigned short* lA0 = As + w * 512;
  unsigned short* lA1 = As + 2048 + w * 512;
  unsigned short* lB0 = Bs + w * 512;
  unsigned short* lB1 = Bs + 2048 + w * 512;

  f32x4 acc[4][4];
#pragma unroll
  for (int i=0;i<4;++i)
#pragma unroll
    for (int j=0;j<4;++j) acc[i][j] = zero4();

  for (int kb = 0; kb < 32; ++kb){
    const int k0 = kb * 32;
    GLL16(Ag + k0,         lA0);
    GLL16(Ag + k0 + 65536, lA1);
    GLL16(Bg + k0,         lB0);
    GLL16(Bg + k0 + 65536, lB1);
    __syncthreads();
    short8 af[4], bf_[4];
#pragma unroll
    for (int i=0;i<4;++i) af[i]  = *(const short8*)(As + (wm*64 + i*16 + lq)*32 + lg*8);
#pragma unroll
    for (int j=0;j<4;++j) bf_[j] = *(const short8*)(Bs + (wn*64 + j*16 + lq)*32 + lg*8);
#pragma unroll
    for (int i=0;i<4;++i)
#pragma unroll
      for (int j=0;j<4;++j)
        acc[i][j] = __builtin_amdgcn_mfma_f32_16x16x32_bf16(af[i], bf_[j], acc[i][j], 0, 0, 0);
    __syncthreads();
  }

  const int mrow = m0 + wm*64, ncol = n0 + wn*64;
  float bj[4];
#pragma unroll
  for (int j=0;j<4;++j) bj[j] = bias[ncol + j*16 + lq];
#pragma unroll
  for (int i=0;i<4;++i)
#pragma unroll
    for (int j=0;j<4;++j)
#pragma unroll
      for (int r=0;r<4;++r){
        float v = acc[i][j][r] + bj[j];
        int m = mrow + i*16 + lg*4 + r;
        int n = ncol + j*16 + lq;
        if (MODE == 0){
          int bb = m >> 10, sI = m & 1023, h = n >> 6, d = n & 63;
          ((unsigned short*)outp)[(size_t)z*8388608 + (((size_t)bb*16 + h)*1024 + sI)*64 + d] = f2bf(v);
        } else {
          ((float*)outp)[(size_t)m*1024 + n] = v;
        }
      }
}

// ---------------- V [bh][s][d] -> Vt [bh][d][s] ----------------
__global__ __launch_bounds__(256) void transpose_v(const unsigned short* __restrict__ V,
                                                   unsigned short* __restrict__ Vt){
  int idx = blockIdx.x * 256 + threadIdx.x;
  int s8 = idx & 127, d = (idx >> 7) & 63, bh = idx >> 13;
  const unsigned short* src = V + (size_t)bh*65536 + (size_t)s8*8*64 + d;
  short8 o;
#pragma unroll
  for (int j=0;j<8;++j) o[j] = (short)src[(size_t)j*64];
  *(short8*)(Vt + (size_t)bh*65536 + (size_t)d*1024 + (size_t)s8*8) = o;
}

// ---------------- fused attention with cross-head mix (v8: 16-wave block, TLP 4/SIMD) ----------------
// grid 256 blocks (bid&7=batch -> XCD-local K/V), 1024 threads (16 waves), 1 block/CU.
// QBLK=32, KVBLK=32, 32 iters. Wave w = aQ(w&3) + 4*iw((w>>2)&1) + 8*ks0(w>>3):
//   QK^T: heads 4aQ..+3, q-half iw, k-half ks0.
//   mix:  q-rows {2w, 2w+1} (one 32x32x16 MFMA each).
//   softmax+PV: output head g = w, both q-halves i=0,1.
// PV operand-swapped (acco col = q = lane&15): no rescale shuffles.
__global__ __launch_bounds__(1024,1) void attn_fused(const unsigned short* __restrict__ Q,
    const unsigned short* __restrict__ K, const unsigned short* __restrict__ Vt,
    const unsigned* __restrict__ MB, const unsigned short* __restrict__ EmT,
    unsigned short* __restrict__ AO){
  __shared__ __align__(16) unsigned short sraw[16384]; // 32KB [q32][k32][h16] swizzled
  __shared__ __align__(16) unsigned short smix[16384]; // 32KB [g16][q32][k32] swizzled
  const int tid = threadIdx.x;
  const int w = tid >> 6, ln = tid & 63;
  const int lq = ln & 15, lg = ln >> 4;
  const int l5 = ln & 31, h5 = ln >> 5;
  const int bid = blockIdx.x;
  const int bb = bid & 7, q0 = (bid >> 3) * 32;
  const int aQ = w & 3, iw = (w >> 2) & 1, ks0 = w >> 3;
  const int g = w;                                    // output head for softmax/PV

  const unsigned short* Qb = Q  + ((size_t)bb*16 + 4*aQ) * 65536;
  const unsigned short* Kb = K  + ((size_t)bb*16 + 4*aQ) * 65536 + (size_t)(ks0*16 + lq)*64 + lg*8;
  const unsigned short* Vb = Vt + ((size_t)bb*16 + g) * 65536;
  const unsigned* Mwp = MB + (size_t)bb*32768 + (size_t)(q0 + lq)*32;

  // Em A-frag for 32x32x16: lane: EmT[l5][h5*8 + j]
  short8 emA = *(const short8*)(EmT + l5*16 + h5*8);

  // Q frags (persistent): rows q0 + iw*16 + lq
  short8 qf[4][2];
#pragma unroll
  for (int hh=0; hh<4; ++hh)
#pragma unroll
    for (int ks=0; ks<2; ++ks)
      qf[hh][ks] = *(const short8*)(Qb + (size_t)hh*65536 + (size_t)(q0 + iw*16 + lq)*64 + ks*32 + lg*8);

  f32x4 acco[2][4];
#pragma unroll
  for (int i=0;i<2;++i)
#pragma unroll
    for (int n=0;n<4;++n) acco[i][n] = zero4();
  float mst[2] = {-3.0e38f,-3.0e38f};
  float lst[2] = {0.f,0.f};

  for (int kt = 0; kt < 32; ++kt){
    const int kb = kt*32;
    // ---- QK^T: 4 heads x (16q x 16k) ----
    f32x4 accs[4];
#pragma unroll
    for (int hh=0; hh<4; ++hh){
      short8 k0 = *(const short8*)(Kb + (size_t)hh*65536 + (size_t)kb*64);
      short8 k1 = *(const short8*)(Kb + (size_t)hh*65536 + (size_t)kb*64 + 32);
      accs[hh] = __builtin_amdgcn_mfma_f32_16x16x32_bf16(qf[hh][0], k0, zero4(), 0,0,0);
      accs[hh] = __builtin_amdgcn_mfma_f32_16x16x32_bf16(qf[hh][1], k1, accs[hh], 0,0,0);
    }
    // ---- prefetch V + mask for this tile (consumed after 2 barriers) ----
    short8 vfr[4];
#pragma unroll
    for (int n=0;n<4;++n)
      vfr[n] = *(const short8*)(Vb + (size_t)(n*16 + lq)*1024 + kb + lg*8);
    const unsigned mw0 = Mwp[kt];
    const unsigned mw1 = Mwp[512 + kt];
    // ---- write raw scores: sraw[q][k][h], 4 heads per 8B ----
#pragma unroll
    for (int r=0;r<4;++r){
      const int qq = iw*16 + lg*4 + r;
      const int kk = ks0*16 + lq;
      short4v pk;
      pk[0]=(short)f2bf(accs[0][r]); pk[1]=(short)f2bf(accs[1][r]);
      pk[2]=(short)f2bf(accs[2][r]); pk[3]=(short)f2bf(accs[3][r]);
      const int lin = (qq*32 + kk)*32 + aQ*8;
      const int sw  = (((kk>>2)&1)<<4) | (((qq>>2)&3)<<5);
      *(short4v*)((char*)sraw + (lin ^ sw)) = pk;
    }
    BARX();
    // ---- head-mix: one 32x32x16 MFMA per q-row (2 rows per wave) ----
#pragma unroll
    for (int t=0;t<2;++t){
      const int qq = w*2 + t;
      const int lin = (qq*32 + l5)*32 + h5*16;
      const int sw  = (((l5>>2)&1)<<4) | (((qq>>2)&3)<<5);
      short8 sfr = *(const short8*)((const char*)sraw + (lin ^ sw));
      f32x16 md = __builtin_amdgcn_mfma_f32_32x32x16_bf16(emA, sfr, zero16(), 0,0,0);
#pragma unroll
      for (int reg=0;reg<8;++reg){
        const int gg = (reg&3) + 8*(reg>>2) + 4*h5;   // rows < 16 kept
        int ob = gg*2048 + qq*64 + l5*2;
        ob ^= ((gg>>2)&1)<<5;
        *(short*)((char*)smix + ob) = (short)f2bf(md[reg]);
      }
    }
    BARX();
    // ---- online softmax + PV for head g, both q-halves ----
#pragma unroll
    for (int i=0;i<2;++i){
      const unsigned mwv = (i==0) ? mw0 : mw1;
      const unsigned msh = (mwv >> (lg*8)) & 0xffu;
      const int allon = __all((int)(msh == 0xffu));
      const int rb = (g*2048 + (i*16 + lq)*64 + lg*16) ^ (((g>>2)&1)<<5);
      short8 sm8 = *(const short8*)((const char*)smix + rb);
      float s[8];
#pragma unroll
      for (int j=0;j<8;++j) s[j] = bf2f((unsigned short)sm8[j]);
      if (!allon){
#pragma unroll
        for (int j=0;j<8;++j) if (!((msh>>j)&1u)) s[j] = -1.44269504e9f; // -1e9 * log2e
      }
      float m01 = fmaxf(s[0],s[1]), m23 = fmaxf(s[2],s[3]);
      float m45 = fmaxf(s[4],s[5]), m67 = fmaxf(s[6],s[7]);
      float pm = fmaxf(fmaxf(m01,m23), fmaxf(m45,m67));
      pm = fmaxf(pm, __shfl_xor(pm, 16, 64));
      pm = fmaxf(pm, __shfl_xor(pm, 32, 64));
      const float mo = mst[i];
      const float mn = fmaxf(mo, pm);
      const float sc = exp2f(mo - mn);
      float p[8];
#pragma unroll
      for (int j=0;j<8;++j) p[j] = exp2f(s[j] - mn);
      float ps = ((p[0]+p[1]) + (p[2]+p[3])) + ((p[4]+p[5]) + (p[6]+p[7]));
      ps += __shfl_xor(ps, 16, 64);
      ps += __shfl_xor(ps, 32, 64);
      lst[i] = lst[i]*sc + ps;
      mst[i] = mn;
      short8 pa;
#pragma unroll
      for (int j=0;j<8;++j) pa[j] = (short)f2bf(p[j]);
#pragma unroll
      for (int n=0;n<4;++n){
        acco[i][n][0] *= sc; acco[i][n][1] *= sc;
        acco[i][n][2] *= sc; acco[i][n][3] *= sc;
        acco[i][n] = __builtin_amdgcn_mfma_f32_16x16x32_bf16(vfr[n], pa, acco[i][n], 0,0,0);
      }
    }
  }
  // ---- normalize + write AO [B*S][E] bf16 (acco rows = d, cols = q) ----
#pragma unroll
  for (int i=0;i<2;++i){
    const float linv = 1.0f / lst[i];
    const size_t rowb = ((size_t)(bb*1024 + q0 + i*16 + lq))*2048;
#pragma unroll
    for (int n=0;n<4;++n){
      unsigned w0 = (unsigned)f2bf(acco[i][n][0]*linv) | ((unsigned)f2bf(acco[i][n][1]*linv) << 16);
      unsigned w1 = (unsigned)f2bf(acco[i][n][2]*linv) | ((unsigned)f2bf(acco[i][n][3]*linv) << 16);
      const int e = g*64 + n*16 + lg*4;
      *(unsigned*)((char*)AO + rowb + (size_t)e*2    ) = w0;
      *(unsigned*)((char*)AO + rowb + (size_t)e*2 + 4) = w1;
    }
  }
}

// ---------------- host launcher ----------------
extern "C" void kernel_launch(void* const* d_in, const int* in_sizes, int n_in,
                              void* d_out, int out_size, void* d_ws, size_t ws_size,
                              hipStream_t stream){
  const float* x   = (const float*)d_in[0];
  const int*   msk = (const int*)  d_in[1];
  const float* Wq  = (const float*)d_in[2];
  const float* bq  = (const float*)d_in[3];
  const float* Wk  = (const float*)d_in[4];
  const float* bk  = (const float*)d_in[5];
  const float* Wv  = (const float*)d_in[6];
  const float* bv  = (const float*)d_in[7];
  const float* Wo  = (const float*)d_in[8];
  const float* bo  = (const float*)d_in[9];
  const float* ent = (const float*)d_in[10];

  char* ws = (char*)d_ws;
  unsigned short* xb  = (unsigned short*)(ws);                 // 16 MiB (reused as Vt)
  unsigned short* Wb  = (unsigned short*)(ws + 16777216);      // 4 x 2 MiB bf16 weights
  unsigned short* qkv = (unsigned short*)(ws + 25165824);      // Q,K,V: 3 x 16 MiB
  unsigned short* EmT = (unsigned short*)(ws + 75497472);      // 1 KiB
  unsigned*       MB  = (unsigned*)     (ws + 75499520);       // 1 MiB bit-packed mask
  unsigned short* Vt  = xb;
  unsigned short* AO  = qkv + (size_t)2*8388608;

  cast_f32_bf16<<<4096, 256, 0, stream>>>(x,  xb,            1048576);
  cast_f32_bf16<<<512,  256, 0, stream>>>(Wq, Wb,            131072);
  cast_f32_bf16<<<512,  256, 0, stream>>>(Wk, Wb + 1048576,  131072);
  cast_f32_bf16<<<512,  256, 0, stream>>>(Wv, Wb + 2097152,  131072);
  cast_f32_bf16<<<512,  256, 0, stream>>>(Wo, Wb + 3145728,  131072);
  prep_em<<<1, 256, 0, stream>>>(ent, EmT);
  prep_maskbits<<<1024, 256, 0, stream>>>(msk, MB);

  gemm_bt<0><<<dim3(8,64,3), 256, 0, stream>>>(xb, Wb, bq, bk, bv, (void*)qkv);
  transpose_v<<<4096, 256, 0, stream>>>(qkv + (size_t)2*8388608, Vt);
  attn_fused<<<256, 1024, 0, stream>>>(qkv, qkv + 8388608, Vt, MB, EmT, AO);
  gemm_bt<1><<<dim3(8,64,1), 256, 0, stream>>>(AO, Wb + 3145728, bo, bo, bo, d_out);

  (void)in_sizes; (void)n_in; (void)out_size; (void)ws_size;
}

// Round 10
// 465.487 us; speedup vs baseline: 1.0191x; 1.0191x over previous
//
#include <hip/hip_runtime.h>

#define DEVINL static __device__ __forceinline__

typedef __attribute__((ext_vector_type(4)))  float f32x4;
typedef __attribute__((ext_vector_type(16))) float f32x16;
typedef __attribute__((ext_vector_type(4)))  float float4_t;
typedef __attribute__((ext_vector_type(8)))  short short8;
typedef __attribute__((ext_vector_type(4)))  short short4v;
typedef __attribute__((ext_vector_type(4)))  int   int4v;

DEVINL unsigned short f2bf(float f){
  union { float f; unsigned int u; } x; x.f = f;
  return (unsigned short)((x.u + 0x7fffu + ((x.u >> 16) & 1u)) >> 16);
}
DEVINL float bf2f(unsigned short h){
  union { unsigned int u; float f; } x; x.u = ((unsigned int)h) << 16;
  return x.f;
}
DEVINL f32x4 zero4(){ f32x4 z; z[0]=0.f; z[1]=0.f; z[2]=0.f; z[3]=0.f; return z; }
DEVINL f32x16 zero16(){ f32x16 z;
#pragma unroll
  for (int e=0;e<16;++e) z[e]=0.f;
  return z; }

// Rule-18-correct barrier: drain LDS ops only; sched_barrier fences stop hipcc
// from moving LDS ops / MFMAs across the inline-asm waitcnt.
#define BARX() do{ \
  __builtin_amdgcn_sched_barrier(0); \
  asm volatile("s_waitcnt lgkmcnt(0)" ::: "memory"); \
  __builtin_amdgcn_sched_barrier(0); \
  __builtin_amdgcn_s_barrier(); \
  __builtin_amdgcn_sched_barrier(0); \
}while(0)

// async global->LDS, 16B per lane
#define GLL16(gp, lp) __builtin_amdgcn_global_load_lds( \
    (const __attribute__((address_space(1))) void*)(gp), \
    (__attribute__((address_space(3))) void*)(lp), 16, 0, 0)

// ---------------- prep: f32 -> bf16 casts ----------------
__global__ __launch_bounds__(256) void cast_f32_bf16(const float* __restrict__ src,
                                                     unsigned short* __restrict__ dst, int n8){
  int i = blockIdx.x * 256 + threadIdx.x;
  if (i >= n8) return;
  const float4_t* s = (const float4_t*)src;
  float4_t a = s[2*i], b = s[2*i+1];
  short8 o;
  o[0]=(short)f2bf(a[0]); o[1]=(short)f2bf(a[1]); o[2]=(short)f2bf(a[2]); o[3]=(short)f2bf(a[3]);
  o[4]=(short)f2bf(b[0]); o[5]=(short)f2bf(b[1]); o[6]=(short)f2bf(b[2]); o[7]=(short)f2bf(b[3]);
  *(short8*)(dst + (size_t)i*8) = o;
}

// EmT[g][h] = softmax(ent,axis=-1)[h][g] * (log2(e)/sqrt(D)); rows g=16..31 zero-padded.
__global__ __launch_bounds__(256) void prep_em(const float* __restrict__ ent,
                                               unsigned short* __restrict__ EmT){
  int t = threadIdx.x;
  if (t < 16){
    float v[16]; float mx = -3.0e38f;
#pragma unroll
    for (int j=0;j<16;++j){ v[j] = ent[t*16 + j]; mx = fmaxf(mx, v[j]); }
    float s = 0.f;
#pragma unroll
    for (int j=0;j<16;++j){ v[j] = __expf(v[j]-mx); s += v[j]; }
    float inv = (1.f/s) * 0.125f * 1.4426950408889634f;
#pragma unroll
    for (int j=0;j<16;++j) EmT[j*16 + t] = f2bf(v[j]*inv);
  }
  EmT[256 + t] = 0; // zero pad rows 16..31
}

// ---------------- mask [B][1][S][S] int32 -> bit-packed [B][S][S/32] ----------------
__global__ __launch_bounds__(256) void prep_maskbits(const int* __restrict__ mask,
                                                     unsigned* __restrict__ mb){
  int id = blockIdx.x * 256 + threadIdx.x;   // 262144 words
  const int* src = mask + (size_t)id * 32;
  unsigned word = 0u;
#pragma unroll
  for (int c=0;c<8;++c){
    int4v v = *(const int4v*)(src + c*4);
    word |= (unsigned)(v[0]!=0) << (c*4)
          | (unsigned)(v[1]!=0) << (c*4+1)
          | (unsigned)(v[2]!=0) << (c*4+2)
          | (unsigned)(v[3]!=0) << (c*4+3);
  }
  mb[id] = word;
}

// ---------------- GEMM: C = A(bf16,[M][1024]) * W^T(bf16,[N][K]) + bias ----------------
template<int MODE>
__global__ __launch_bounds__(256) void gemm_bt(const unsigned short* __restrict__ A,
                                               const unsigned short* __restrict__ W4,
                                               const float* __restrict__ bias0,
                                               const float* __restrict__ bias1,
                                               const float* __restrict__ bias2,
                                               void* __restrict__ outp){
  __shared__ __align__(16) unsigned short As[4096];
  __shared__ __align__(16) unsigned short Bs[4096];
  const int tid = threadIdx.x;
  const int w = tid >> 6, ln = tid & 63;
  const int wm = w >> 1, wn = w & 1;
  const int lq = ln & 15, lg = ln >> 4;
  const int m0 = blockIdx.y * 128, n0 = blockIdx.x * 128;
  const int z = blockIdx.z;
  const unsigned short* Bt = W4 + (size_t)z * 1048576;
  const float* bias = (z == 0) ? bias0 : ((z == 1) ? bias1 : bias2);

  const unsigned short* Ag = A  + (size_t)(m0 + (tid >> 2)) * 1024 + (tid & 3) * 8;
  const unsigned short* Bg = Bt + (size_t)(n0 + (tid >> 2)) * 1024 + (tid & 3) * 8;
  unsigned short* lA0 = As + w * 512;
  unsigned short* lA1 = As + 2048 + w * 512;
  unsigned short* lB0 = Bs + w * 512;
  unsigned short* lB1 = Bs + 2048 + w * 512;

  f32x4 acc[4][4];
#pragma unroll
  for (int i=0;i<4;++i)
#pragma unroll
    for (int j=0;j<4;++j) acc[i][j] = zero4();

  for (int kb = 0; kb < 32; ++kb){
    const int k0 = kb * 32;
    GLL16(Ag + k0,         lA0);
    GLL16(Ag + k0 + 65536, lA1);
    GLL16(Bg + k0,         lB0);
    GLL16(Bg + k0 + 65536, lB1);
    __syncthreads();
    short8 af[4], bf_[4];
#pragma unroll
    for (int i=0;i<4;++i) af[i]  = *(const short8*)(As + (wm*64 + i*16 + lq)*32 + lg*8);
#pragma unroll
    for (int j=0;j<4;++j) bf_[j] = *(const short8*)(Bs + (wn*64 + j*16 + lq)*32 + lg*8);
#pragma unroll
    for (int i=0;i<4;++i)
#pragma unroll
      for (int j=0;j<4;++j)
        acc[i][j] = __builtin_amdgcn_mfma_f32_16x16x32_bf16(af[i], bf_[j], acc[i][j], 0, 0, 0);
    __syncthreads();
  }

  const int mrow = m0 + wm*64, ncol = n0 + wn*64;
  float bj[4];
#pragma unroll
  for (int j=0;j<4;++j) bj[j] = bias[ncol + j*16 + lq];
#pragma unroll
  for (int i=0;i<4;++i)
#pragma unroll
    for (int j=0;j<4;++j)
#pragma unroll
      for (int r=0;r<4;++r){
        float v = acc[i][j][r] + bj[j];
        int m = mrow + i*16 + lg*4 + r;
        int n = ncol + j*16 + lq;
        if (MODE == 0){
          int bb = m >> 10, sI = m & 1023, h = n >> 6, d = n & 63;
          ((unsigned short*)outp)[(size_t)z*8388608 + (((size_t)bb*16 + h)*1024 + sI)*64 + d] = f2bf(v);
        } else {
          ((float*)outp)[(size_t)m*1024 + n] = v;
        }
      }
}

// ---------------- V [bh][s][d] -> Vt [bh][d][s] ----------------
__global__ __launch_bounds__(256) void transpose_v(const unsigned short* __restrict__ V,
                                                   unsigned short* __restrict__ Vt){
  int idx = blockIdx.x * 256 + threadIdx.x;
  int s8 = idx & 127, d = (idx >> 7) & 63, bh = idx >> 13;
  const unsigned short* src = V + (size_t)bh*65536 + (size_t)s8*8*64 + d;
  short8 o;
#pragma unroll
  for (int j=0;j<8;++j) o[j] = (short)src[(size_t)j*64];
  *(short8*)(Vt + (size_t)bh*65536 + (size_t)d*1024 + (size_t)s8*8) = o;
}

// ---------------- fused attention with cross-head mix (v9: SLIM, 2 blocks/CU target) ----------------
// grid 512 blocks (bid&7=batch -> XCD-local K/V), 512 threads (8 waves), QBLK=16, KVBLK=32.
// State slimmed to fit the gfx950 UNIFIED VGPR+AGPR budget of 128/wave at 4 waves/SIMD:
//   - Q frags reloaded from global each iter (block Q footprint 32KB -> L1/L2-hot)
//   - V frags loaded in-phase (transient), no cross-barrier prefetch
// PV operand-swapped (acco col = q = lane&15): no rescale shuffles.
__global__ __launch_bounds__(512,4) void attn_fused(const unsigned short* __restrict__ Q,
    const unsigned short* __restrict__ K, const unsigned short* __restrict__ Vt,
    const unsigned* __restrict__ MB, const unsigned short* __restrict__ EmT,
    unsigned short* __restrict__ AO){
  __shared__ __align__(16) unsigned short sraw[8192]; // 16KB [q16][k32][h16] swizzled
  __shared__ __align__(16) unsigned short smix[8192]; // 16KB [g16][q16][k32] swizzled
  const int tid = threadIdx.x;
  const int w = tid >> 6, ln = tid & 63;
  const int lq = ln & 15, lg = ln >> 4;
  const int l5 = ln & 31, h5 = ln >> 5;
  const int bid = blockIdx.x;
  const int bb = bid & 7, q0 = (bid >> 3) * 16;
  const int aQ = w & 3, n0 = w >> 2, g0 = w * 2;

  const unsigned short* Qb = Q  + ((size_t)bb*16 + 4*aQ) * 65536 + (size_t)(q0 + lq)*64 + lg*8;
  const unsigned short* Kb = K  + ((size_t)bb*16 + 4*aQ) * 65536 + (size_t)(n0*16 + lq)*64 + lg*8;
  const unsigned short* Vb = Vt + ((size_t)bb*16 + g0) * 65536 + (size_t)lq*1024 + lg*8;
  const unsigned* Mwp = MB + (size_t)bb*32768 + (size_t)(q0 + lq)*32;

  // Em A-frag for 32x32x16: lane: EmT[l5][h5*8 + j]
  short8 emA = *(const short8*)(EmT + l5*16 + h5*8);

  f32x4 acco[2][4];
#pragma unroll
  for (int a=0;a<2;++a)
#pragma unroll
    for (int n=0;n<4;++n) acco[a][n] = zero4();
  float mst[2] = {-3.0e38f,-3.0e38f};
  float lst[2] = {0.f,0.f};

  const int kk = n0*16 + lq;

  for (int kt = 0; kt < 32; ++kt){
    const int kb = kt*32;
    const unsigned mw = Mwp[kt];
    // ---- QK^T: 4 heads x (16q x 16k), Q reloaded (L1/L2-hot) ----
    f32x4 accs[4];
#pragma unroll
    for (int hh=0; hh<4; ++hh){
      short8 q0f = *(const short8*)(Qb + (size_t)hh*65536);
      short8 q1f = *(const short8*)(Qb + (size_t)hh*65536 + 32);
      short8 k0f = *(const short8*)(Kb + (size_t)hh*65536 + (size_t)kb*64);
      short8 k1f = *(const short8*)(Kb + (size_t)hh*65536 + (size_t)kb*64 + 32);
      accs[hh] = __builtin_amdgcn_mfma_f32_16x16x32_bf16(q0f, k0f, zero4(), 0,0,0);
      accs[hh] = __builtin_amdgcn_mfma_f32_16x16x32_bf16(q1f, k1f, accs[hh], 0,0,0);
    }
    // ---- pack + store raw scores: sraw[q][k][h], 4 heads per 8B ----
#pragma unroll
    for (int r=0;r<4;++r){
      const int qq = lg*4 + r;
      short4v pk;
      pk[0]=(short)f2bf(accs[0][r]); pk[1]=(short)f2bf(accs[1][r]);
      pk[2]=(short)f2bf(accs[2][r]); pk[3]=(short)f2bf(accs[3][r]);
      const int lin = (qq*32 + kk)*32 + aQ*8;
      const int sw  = (((kk>>2)&1)<<4) | (((qq>>2)&3)<<5);
      *(short4v*)((char*)sraw + (lin ^ sw)) = pk;
    }
    BARX();
    // ---- head-mix: one 32x32x16 MFMA per q-row (2 rows per wave) ----
#pragma unroll
    for (int t=0;t<2;++t){
      const int qq = w*2 + t;
      const int lin = (qq*32 + l5)*32 + h5*16;
      const int sw  = (((l5>>2)&1)<<4) | (((qq>>2)&3)<<5);
      short8 sfr = *(const short8*)((const char*)sraw + (lin ^ sw));
      f32x16 md = __builtin_amdgcn_mfma_f32_32x32x16_bf16(emA, sfr, zero16(), 0,0,0);
#pragma unroll
      for (int reg=0;reg<8;++reg){
        const int gg = (reg&3) + 8*(reg>>2) + 4*h5;   // rows < 16 kept
        int ob = gg*1024 + qq*64 + l5*2;
        ob ^= ((gg>>2)&1)<<6;
        *(short*)((char*)smix + ob) = (short)f2bf(md[reg]);
      }
    }
    BARX();
    // ---- online softmax + PV (state & acco indexed by q = lane&15) ----
    const unsigned msh = (mw >> (lg*8)) & 0xffu;
    const int allon = __all((int)(msh == 0xffu));
#pragma unroll
    for (int hh=0; hh<2; ++hh){
      const int gg = g0 + hh;
      // V frags for this head (transient; issued before softmax chain)
      short8 vfr[4];
#pragma unroll
      for (int n=0;n<4;++n)
        vfr[n] = *(const short8*)(Vb + (size_t)hh*65536 + (size_t)n*16384 + kb);
      const int rb = (gg*1024 + lq*64 + lg*16) ^ (((gg>>2)&1)<<6);
      short8 sm8 = *(const short8*)((const char*)smix + rb);
      float s[8];
#pragma unroll
      for (int j=0;j<8;++j) s[j] = bf2f((unsigned short)sm8[j]);
      if (!allon){
#pragma unroll
        for (int j=0;j<8;++j) if (!((msh>>j)&1u)) s[j] = -1.44269504e9f; // -1e9 * log2e
      }
      float m01 = fmaxf(s[0],s[1]), m23 = fmaxf(s[2],s[3]);
      float m45 = fmaxf(s[4],s[5]), m67 = fmaxf(s[6],s[7]);
      float pm = fmaxf(fmaxf(m01,m23), fmaxf(m45,m67));
      pm = fmaxf(pm, __shfl_xor(pm, 16, 64));
      pm = fmaxf(pm, __shfl_xor(pm, 32, 64));
      const float mo = mst[hh];
      const float mn = fmaxf(mo, pm);
      const float sc = exp2f(mo - mn);
      float p[8];
#pragma unroll
      for (int j=0;j<8;++j) p[j] = exp2f(s[j] - mn);
      float ps = ((p[0]+p[1]) + (p[2]+p[3])) + ((p[4]+p[5]) + (p[6]+p[7]));
      ps += __shfl_xor(ps, 16, 64);
      ps += __shfl_xor(ps, 32, 64);
      lst[hh] = lst[hh]*sc + ps;
      mst[hh] = mn;
      short8 pa;
#pragma unroll
      for (int j=0;j<8;++j) pa[j] = (short)f2bf(p[j]);
#pragma unroll
      for (int n=0;n<4;++n){
        acco[hh][n][0] *= sc; acco[hh][n][1] *= sc;
        acco[hh][n][2] *= sc; acco[hh][n][3] *= sc;
        acco[hh][n] = __builtin_amdgcn_mfma_f32_16x16x32_bf16(vfr[n], pa, acco[hh][n], 0,0,0);
      }
    }
  }
  // ---- normalize + write AO [B*S][E] bf16 (acco rows = d, cols = q = lq) ----
#pragma unroll
  for (int hh=0; hh<2; ++hh){
    const int gg = g0 + hh;
    const float linv = 1.0f / lst[hh];
    const size_t rowb = ((size_t)(bb*1024 + q0 + lq))*2048;
#pragma unroll
    for (int n=0;n<4;++n){
      unsigned w0 = (unsigned)f2bf(acco[hh][n][0]*linv) | ((unsigned)f2bf(acco[hh][n][1]*linv) << 16);
      unsigned w1 = (unsigned)f2bf(acco[hh][n][2]*linv) | ((unsigned)f2bf(acco[hh][n][3]*linv) << 16);
      const int e = gg*64 + n*16 + lg*4;
      *(unsigned*)((char*)AO + rowb + (size_t)e*2    ) = w0;
      *(unsigned*)((char*)AO + rowb + (size_t)e*2 + 4) = w1;
    }
  }
}

// ---------------- host launcher ----------------
extern "C" void kernel_launch(void* const* d_in, const int* in_sizes, int n_in,
                              void* d_out, int out_size, void* d_ws, size_t ws_size,
                              hipStream_t stream){
  const float* x   = (const float*)d_in[0];
  const int*   msk = (const int*)  d_in[1];
  const float* Wq  = (const float*)d_in[2];
  const float* bq  = (const float*)d_in[3];
  const float* Wk  = (const float*)d_in[4];
  const float* bk  = (const float*)d_in[5];
  const float* Wv  = (const float*)d_in[6];
  const float* bv  = (const float*)d_in[7];
  const float* Wo  = (const float*)d_in[8];
  const float* bo  = (const float*)d_in[9];
  const float* ent = (const float*)d_in[10];

  char* ws = (char*)d_ws;
  unsigned short* xb  = (unsigned short*)(ws);                 // 16 MiB (reused as Vt)
  unsigned short* Wb  = (unsigned short*)(ws + 16777216);      // 4 x 2 MiB bf16 weights
  unsigned short* qkv = (unsigned short*)(ws + 25165824);      // Q,K,V: 3 x 16 MiB
  unsigned short* EmT = (unsigned short*)(ws + 75497472);      // 1 KiB
  unsigned*       MB  = (unsigned*)     (ws + 75499520);       // 1 MiB bit-packed mask
  unsigned short* Vt  = xb;
  unsigned short* AO  = qkv + (size_t)2*8388608;

  cast_f32_bf16<<<4096, 256, 0, stream>>>(x,  xb,            1048576);
  cast_f32_bf16<<<512,  256, 0, stream>>>(Wq, Wb,            131072);
  cast_f32_bf16<<<512,  256, 0, stream>>>(Wk, Wb + 1048576,  131072);
  cast_f32_bf16<<<512,  256, 0, stream>>>(Wv, Wb + 2097152,  131072);
  cast_f32_bf16<<<512,  256, 0, stream>>>(Wo, Wb + 3145728,  131072);
  prep_em<<<1, 256, 0, stream>>>(ent, EmT);
  prep_maskbits<<<1024, 256, 0, stream>>>(msk, MB);

  gemm_bt<0><<<dim3(8,64,3), 256, 0, stream>>>(xb, Wb, bq, bk, bv, (void*)qkv);
  transpose_v<<<4096, 256, 0, stream>>>(qkv + (size_t)2*8388608, Vt);
  attn_fused<<<512, 512, 0, stream>>>(qkv, qkv + 8388608, Vt, MB, EmT, AO);
  gemm_bt<1><<<dim3(8,64,1), 256, 0, stream>>>(AO, Wb + 3145728, bo, bo, bo, d_out);

  (void)in_sizes; (void)n_in; (void)out_size; (void)ws_size;
}

// Round 11
// 432.892 us; speedup vs baseline: 1.0959x; 1.0753x over previous
//
#include <hip/hip_runtime.h>
#include <hip/hip_bf16.h>

#define DEVINL static __device__ __forceinline__

typedef __attribute__((ext_vector_type(4)))  float f32x4;
typedef __attribute__((ext_vector_type(16))) float f32x16;
typedef __attribute__((ext_vector_type(4)))  float float4_t;
typedef __attribute__((ext_vector_type(8)))  short short8;
typedef __attribute__((ext_vector_type(4)))  short short4v;
typedef __attribute__((ext_vector_type(4)))  int   int4v;
typedef __attribute__((ext_vector_type(2)))  unsigned u32x2;
typedef __attribute__((ext_vector_type(4)))  unsigned u32x4;

// native single-op converts (v_cvt_pk_bf16_f32); RNE matches reference rounding
DEVINL unsigned short f2bf(float f){
  __hip_bfloat16 h = __float2bfloat16(f);
  unsigned short u; __builtin_memcpy(&u, &h, 2); return u;
}
DEVINL unsigned pk2(float lo, float hi){
  __hip_bfloat162 h2 = __float22bfloat162_rn(make_float2(lo, hi));
  unsigned u; __builtin_memcpy(&u, &h2, 4); return u;
}
DEVINL float bf2f(unsigned short h){
  union { unsigned int u; float f; } x; x.u = ((unsigned int)h) << 16;
  return x.f;
}
DEVINL f32x4 zero4(){ f32x4 z; z[0]=0.f; z[1]=0.f; z[2]=0.f; z[3]=0.f; return z; }
DEVINL f32x16 zero16(){ f32x16 z;
#pragma unroll
  for (int e=0;e<16;++e) z[e]=0.f;
  return z; }

// Rule-18-correct barrier: drain LDS ops only; sched_barrier fences stop hipcc
// from moving LDS ops / MFMAs across the inline-asm waitcnt. (R8-verified.)
#define BARX() do{ \
  __builtin_amdgcn_sched_barrier(0); \
  asm volatile("s_waitcnt lgkmcnt(0)" ::: "memory"); \
  __builtin_amdgcn_sched_barrier(0); \
  __builtin_amdgcn_s_barrier(); \
  __builtin_amdgcn_sched_barrier(0); \
}while(0)

// async global->LDS, 16B per lane
#define GLL16(gp, lp) __builtin_amdgcn_global_load_lds( \
    (const __attribute__((address_space(1))) void*)(gp), \
    (__attribute__((address_space(3))) void*)(lp), 16, 0, 0)

// ---------------- prep: f32 -> bf16 casts ----------------
__global__ __launch_bounds__(256) void cast_f32_bf16(const float* __restrict__ src,
                                                     unsigned short* __restrict__ dst, int n8){
  int i = blockIdx.x * 256 + threadIdx.x;
  if (i >= n8) return;
  const float4_t* s = (const float4_t*)src;
  float4_t a = s[2*i], b = s[2*i+1];
  u32x4 o;
  o[0]=pk2(a[0],a[1]); o[1]=pk2(a[2],a[3]);
  o[2]=pk2(b[0],b[1]); o[3]=pk2(b[2],b[3]);
  *(u32x4*)(dst + (size_t)i*8) = o;
}

// EmT[g][h] = softmax(ent,axis=-1)[h][g] * (log2(e)/sqrt(D)); rows g=16..31 zero-padded.
__global__ __launch_bounds__(256) void prep_em(const float* __restrict__ ent,
                                               unsigned short* __restrict__ EmT){
  int t = threadIdx.x;
  if (t < 16){
    float v[16]; float mx = -3.0e38f;
#pragma unroll
    for (int j=0;j<16;++j){ v[j] = ent[t*16 + j]; mx = fmaxf(mx, v[j]); }
    float s = 0.f;
#pragma unroll
    for (int j=0;j<16;++j){ v[j] = __expf(v[j]-mx); s += v[j]; }
    float inv = (1.f/s) * 0.125f * 1.4426950408889634f;
#pragma unroll
    for (int j=0;j<16;++j) EmT[j*16 + t] = f2bf(v[j]*inv);
  }
  EmT[256 + t] = 0; // zero pad rows 16..31
}

// ---------------- mask [B][1][S][S] int32 -> bit-packed [B][S][S/32] ----------------
__global__ __launch_bounds__(256) void prep_maskbits(const int* __restrict__ mask,
                                                     unsigned* __restrict__ mb){
  int id = blockIdx.x * 256 + threadIdx.x;   // 262144 words
  const int* src = mask + (size_t)id * 32;
  unsigned word = 0u;
#pragma unroll
  for (int c=0;c<8;++c){
    int4v v = *(const int4v*)(src + c*4);
    word |= (unsigned)(v[0]!=0) << (c*4)
          | (unsigned)(v[1]!=0) << (c*4+1)
          | (unsigned)(v[2]!=0) << (c*4+2)
          | (unsigned)(v[3]!=0) << (c*4+3);
  }
  mb[id] = word;
}

// ---------------- GEMM: C = A(bf16,[M][1024]) * W^T(bf16,[N][K]) + bias ----------------
template<int MODE>
__global__ __launch_bounds__(256) void gemm_bt(const unsigned short* __restrict__ A,
                                               const unsigned short* __restrict__ W4,
                                               const float* __restrict__ bias0,
                                               const float* __restrict__ bias1,
                                               const float* __restrict__ bias2,
                                               void* __restrict__ outp){
  __shared__ __align__(16) unsigned short As[4096];
  __shared__ __align__(16) unsigned short Bs[4096];
  const int tid = threadIdx.x;
  const int w = tid >> 6, ln = tid & 63;
  const int wm = w >> 1, wn = w & 1;
  const int lq = ln & 15, lg = ln >> 4;
  const int m0 = blockIdx.y * 128, n0 = blockIdx.x * 128;
  const int z = blockIdx.z;
  const unsigned short* Bt = W4 + (size_t)z * 1048576;
  const float* bias = (z == 0) ? bias0 : ((z == 1) ? bias1 : bias2);

  const unsigned short* Ag = A  + (size_t)(m0 + (tid >> 2)) * 1024 + (tid & 3) * 8;
  const unsigned short* Bg = Bt + (size_t)(n0 + (tid >> 2)) * 1024 + (tid & 3) * 8;
  unsigned short* lA0 = As + w * 512;
  unsigned short* lA1 = As + 2048 + w * 512;
  unsigned short* lB0 = Bs + w * 512;
  unsigned short* lB1 = Bs + 2048 + w * 512;

  f32x4 acc[4][4];
#pragma unroll
  for (int i=0;i<4;++i)
#pragma unroll
    for (int j=0;j<4;++j) acc[i][j] = zero4();

  for (int kb = 0; kb < 32; ++kb){
    const int k0 = kb * 32;
    GLL16(Ag + k0,         lA0);
    GLL16(Ag + k0 + 65536, lA1);
    GLL16(Bg + k0,         lB0);
    GLL16(Bg + k0 + 65536, lB1);
    __syncthreads();
    short8 af[4], bf_[4];
#pragma unroll
    for (int i=0;i<4;++i) af[i]  = *(const short8*)(As + (wm*64 + i*16 + lq)*32 + lg*8);
#pragma unroll
    for (int j=0;j<4;++j) bf_[j] = *(const short8*)(Bs + (wn*64 + j*16 + lq)*32 + lg*8);
#pragma unroll
    for (int i=0;i<4;++i)
#pragma unroll
      for (int j=0;j<4;++j)
        acc[i][j] = __builtin_amdgcn_mfma_f32_16x16x32_bf16(af[i], bf_[j], acc[i][j], 0, 0, 0);
    __syncthreads();
  }

  const int mrow = m0 + wm*64, ncol = n0 + wn*64;
  float bj[4];
#pragma unroll
  for (int j=0;j<4;++j) bj[j] = bias[ncol + j*16 + lq];
#pragma unroll
  for (int i=0;i<4;++i)
#pragma unroll
    for (int j=0;j<4;++j)
#pragma unroll
      for (int r=0;r<4;++r){
        float v = acc[i][j][r] + bj[j];
        int m = mrow + i*16 + lg*4 + r;
        int n = ncol + j*16 + lq;
        if (MODE == 0){
          int bb = m >> 10, sI = m & 1023, h = n >> 6, d = n & 63;
          ((unsigned short*)outp)[(size_t)z*8388608 + (((size_t)bb*16 + h)*1024 + sI)*64 + d] = f2bf(v);
        } else {
          ((float*)outp)[(size_t)m*1024 + n] = v;
        }
      }
}

// ---------------- V [bh][s][d] -> Vt [bh][d][s] ----------------
__global__ __launch_bounds__(256) void transpose_v(const unsigned short* __restrict__ V,
                                                   unsigned short* __restrict__ Vt){
  int idx = blockIdx.x * 256 + threadIdx.x;
  int s8 = idx & 127, d = (idx >> 7) & 63, bh = idx >> 13;
  const unsigned short* src = V + (size_t)bh*65536 + (size_t)s8*8*64 + d;
  short8 o;
#pragma unroll
  for (int j=0;j<8;++j) o[j] = (short)src[(size_t)j*64];
  *(short8*)(Vt + (size_t)bh*65536 + (size_t)d*1024 + (size_t)s8*8) = o;
}

// ---------------- fused attention with cross-head mix (v10: skewed 1-barrier pipeline) ----------------
// 512 blocks (bid&7=batch, XCD-local K/V), 8 waves, QBLK=16, KVBLK=64, 16 iters.
// Double-buffered sraw+smix; per iter: A{V/mask loads || QK^T(t+1)->sraw[b^1] ||
// mix(t): sraw[b]->smix[b]} BARX B{softmax+PV(t)}. ONE barrier per iteration.
// PV operand-swapped (acco col = q = lane&15): no rescale shuffles.
__global__ __launch_bounds__(512,2) void attn_fused(const unsigned short* __restrict__ Q,
    const unsigned short* __restrict__ K, const unsigned short* __restrict__ Vt,
    const unsigned* __restrict__ MB, const unsigned short* __restrict__ EmT,
    unsigned short* __restrict__ AO){
  __shared__ __align__(16) unsigned short sraw[2][16384]; // 2x32KB [q16][k64][h16] swizzled
  __shared__ __align__(16) unsigned short smix[2][16384]; // 2x32KB [g16][q16][k64] swizzled
  const int tid = threadIdx.x;
  const int w = tid >> 6, ln = tid & 63;
  const int lq = ln & 15, lg = ln >> 4;
  const int l5 = ln & 31, h5 = ln >> 5;
  const int bid = blockIdx.x;
  const int bb = bid & 7, q0 = (bid >> 3) * 16;
  const int aQ = w & 3, n0 = w >> 2, g0 = w * 2;

  const unsigned short* Qb = Q  + ((size_t)bb*16 + 4*aQ) * 65536;
  const unsigned short* Kb = K  + ((size_t)bb*16 + 4*aQ) * 65536 + (size_t)(n0*32 + lq)*64 + lg*8;
  const unsigned short* Vb = Vt + ((size_t)bb*16 + g0) * 65536;
  const unsigned* Mwp = MB + (size_t)bb*32768 + (size_t)(q0 + lq)*32;

  short8 emA = *(const short8*)(EmT + l5*16 + h5*8);

  short8 qf[4][2];
#pragma unroll
  for (int hh=0; hh<4; ++hh)
#pragma unroll
    for (int ks=0; ks<2; ++ks)
      qf[hh][ks] = *(const short8*)(Qb + (size_t)hh*65536 + (size_t)(q0 + lq)*64 + ks*32 + lg*8);

  f32x4 acco[2][4];
#pragma unroll
  for (int a=0;a<2;++a)
#pragma unroll
    for (int n=0;n<4;++n) acco[a][n] = zero4();
  float mst[2] = {-3.0e38f,-3.0e38f};
  float lst[2] = {0.f,0.f};

  // QK^T for tile KT -> sraw[DB]  (4 heads x 16q x 64k per wave-group)
  auto QKT = [&](int KT, unsigned short* dst){
    const int kb = KT*64;
    f32x4 accs[4][2];
#pragma unroll
    for (int hh=0; hh<4; ++hh){
      short8 kf[2][2];
#pragma unroll
      for (int n=0;n<2;++n)
#pragma unroll
        for (int ks=0;ks<2;++ks)
          kf[n][ks] = *(const short8*)(Kb + (size_t)hh*65536 + (size_t)(kb + n*16)*64 + ks*32);
#pragma unroll
      for (int n=0;n<2;++n){
        accs[hh][n] = __builtin_amdgcn_mfma_f32_16x16x32_bf16(qf[hh][0], kf[n][0], zero4(), 0,0,0);
        accs[hh][n] = __builtin_amdgcn_mfma_f32_16x16x32_bf16(qf[hh][1], kf[n][1], accs[hh][n], 0,0,0);
      }
    }
#pragma unroll
    for (int n=0;n<2;++n)
#pragma unroll
      for (int r=0;r<4;++r){
        const int qq = lg*4 + r;
        const int kk = n0*32 + n*16 + lq;
        u32x2 pk;
        pk[0] = pk2(accs[0][n][r], accs[1][n][r]);
        pk[1] = pk2(accs[2][n][r], accs[3][n][r]);
        const int lin = (qq*64 + kk)*32 + aQ*8;
        const int sw  = (((kk>>2)&1)<<4) | (((qq>>2)&3)<<5);
        *(u32x2*)((char*)dst + (lin ^ sw)) = pk;
      }
  };

  // ---- prologue: QK^T(0) -> sraw[0] ----
  QKT(0, &sraw[0][0]);
  BARX();

  for (int kt = 0; kt < 16; ++kt){
    const int buf = kt & 1;
    const int kb = kt*64;
    // ---- phase A: V+mask loads || QK^T(kt+1) -> sraw[buf^1] || mix(kt) ----
    const u32x2 mw = *(const u32x2*)(Mwp + kt*2);
    short8 vfr[2][4][2];
#pragma unroll
    for (int hh=0;hh<2;++hh)
#pragma unroll
      for (int n=0;n<4;++n)
#pragma unroll
        for (int kh=0;kh<2;++kh)
          vfr[hh][n][kh] = *(const short8*)(Vb + (size_t)hh*65536 + (size_t)(n*16 + lq)*1024 + kb + kh*32 + lg*8);

    if (kt < 15) QKT(kt+1, &sraw[buf^1][0]);

    // mix(kt): sraw[buf] -> smix[buf]; one 32x32x16 MFMA per (q-row, k-half)
#pragma unroll
    for (int t=0;t<4;++t){
      const int qq = w*2 + (t&1);
      const int kh = t>>1;
      const int kk = kh*32 + l5;
      const int lin = (qq*64 + kk)*32 + h5*16;
      const int sw  = (((kk>>2)&1)<<4) | (((qq>>2)&3)<<5);
      short8 sfr = *(const short8*)((const char*)&sraw[buf][0] + (lin ^ sw));
      f32x16 md = __builtin_amdgcn_mfma_f32_32x32x16_bf16(emA, sfr, zero16(), 0,0,0);
#pragma unroll
      for (int reg=0;reg<8;++reg){
        const int gg = (reg&3) + 8*(reg>>2) + 4*h5;   // rows < 16 kept
        int ob = gg*2048 + qq*128 + kk*2;
        ob ^= ((qq&7)<<4) ^ (((gg>>2)&1)<<6);
        *(short*)((char*)&smix[buf][0] + ob) = (short)f2bf(md[reg]);
      }
    }
    BARX();
    // ---- phase B: online softmax + PV(kt) from smix[buf] ----
    const unsigned mb0 = (mw[0] >> (lg*8)) & 0xffu;
    const unsigned mb1 = (mw[1] >> (lg*8)) & 0xffu;
    const int allon = __all((int)((mb0 & mb1) == 0xffu));
#pragma unroll
    for (int hh=0; hh<2; ++hh){
      const int gg = g0 + hh;
      const int swc = ((lq&7)<<4) ^ (((gg>>2)&1)<<6);
      const int base = gg*2048 + lq*128 + lg*16;
      short8 sm0 = *(const short8*)((const char*)&smix[buf][0] + ((base      ) ^ swc));
      short8 sm1 = *(const short8*)((const char*)&smix[buf][0] + ((base + 64 ) ^ swc));
      float s[16];
#pragma unroll
      for (int j=0;j<8;++j){ s[j] = bf2f((unsigned short)sm0[j]); s[8+j] = bf2f((unsigned short)sm1[j]); }
      if (!allon){
#pragma unroll
        for (int j=0;j<8;++j){
          if (!((mb0>>j)&1u)) s[j]    = -1.44269504e9f;
          if (!((mb1>>j)&1u)) s[8+j]  = -1.44269504e9f;
        }
      }
      float m01 = fmaxf(s[0],s[1]),  m23 = fmaxf(s[2],s[3]);
      float m45 = fmaxf(s[4],s[5]),  m67 = fmaxf(s[6],s[7]);
      float m89 = fmaxf(s[8],s[9]),  mab = fmaxf(s[10],s[11]);
      float mcd = fmaxf(s[12],s[13]),mef = fmaxf(s[14],s[15]);
      float pm = fmaxf(fmaxf(fmaxf(m01,m23), fmaxf(m45,m67)),
                       fmaxf(fmaxf(m89,mab), fmaxf(mcd,mef)));
      pm = fmaxf(pm, __shfl_xor(pm, 16, 64));
      pm = fmaxf(pm, __shfl_xor(pm, 32, 64));
      const float mo = mst[hh];
      const float mn = fmaxf(mo, pm);
      const float sc = exp2f(mo - mn);
      float p[16];
#pragma unroll
      for (int j=0;j<16;++j) p[j] = exp2f(s[j] - mn);
      float ps = 0.f;
#pragma unroll
      for (int j=0;j<16;++j) ps += p[j];
      ps += __shfl_xor(ps, 16, 64);
      ps += __shfl_xor(ps, 32, 64);
      lst[hh] = lst[hh]*sc + ps;
      mst[hh] = mn;
      union { short8 s8; u32x4 u4; } pa0, pa1;
      pa0.u4[0]=pk2(p[0],p[1]);   pa0.u4[1]=pk2(p[2],p[3]);
      pa0.u4[2]=pk2(p[4],p[5]);   pa0.u4[3]=pk2(p[6],p[7]);
      pa1.u4[0]=pk2(p[8],p[9]);   pa1.u4[1]=pk2(p[10],p[11]);
      pa1.u4[2]=pk2(p[12],p[13]); pa1.u4[3]=pk2(p[14],p[15]);
#pragma unroll
      for (int n=0;n<4;++n){
        acco[hh][n][0] *= sc; acco[hh][n][1] *= sc;
        acco[hh][n][2] *= sc; acco[hh][n][3] *= sc;
      }
#pragma unroll
      for (int n=0;n<4;++n){
        acco[hh][n] = __builtin_amdgcn_mfma_f32_16x16x32_bf16(vfr[hh][n][0], pa0.s8, acco[hh][n], 0,0,0);
        acco[hh][n] = __builtin_amdgcn_mfma_f32_16x16x32_bf16(vfr[hh][n][1], pa1.s8, acco[hh][n], 0,0,0);
      }
    }
  }
  // ---- normalize + write AO [B*S][E] bf16 (acco rows = d, cols = q = lq) ----
#pragma unroll
  for (int hh=0; hh<2; ++hh){
    const int gg = g0 + hh;
    const float linv = 1.0f / lst[hh];
    const size_t rowb = ((size_t)(bb*1024 + q0 + lq))*2048;
#pragma unroll
    for (int n=0;n<4;++n){
      unsigned w0 = pk2(acco[hh][n][0]*linv, acco[hh][n][1]*linv);
      unsigned w1 = pk2(acco[hh][n][2]*linv, acco[hh][n][3]*linv);
      const int e = gg*64 + n*16 + lg*4;
      *(unsigned*)((char*)AO + rowb + (size_t)e*2    ) = w0;
      *(unsigned*)((char*)AO + rowb + (size_t)e*2 + 4) = w1;
    }
  }
}

// ---------------- host launcher ----------------
extern "C" void kernel_launch(void* const* d_in, const int* in_sizes, int n_in,
                              void* d_out, int out_size, void* d_ws, size_t ws_size,
                              hipStream_t stream){
  const float* x   = (const float*)d_in[0];
  const int*   msk = (const int*)  d_in[1];
  const float* Wq  = (const float*)d_in[2];
  const float* bq  = (const float*)d_in[3];
  const float* Wk  = (const float*)d_in[4];
  const float* bk  = (const float*)d_in[5];
  const float* Wv  = (const float*)d_in[6];
  const float* bv  = (const float*)d_in[7];
  const float* Wo  = (const float*)d_in[8];
  const float* bo  = (const float*)d_in[9];
  const float* ent = (const float*)d_in[10];

  char* ws = (char*)d_ws;
  unsigned short* xb  = (unsigned short*)(ws);                 // 16 MiB (reused as Vt)
  unsigned short* Wb  = (unsigned short*)(ws + 16777216);      // 4 x 2 MiB bf16 weights
  unsigned short* qkv = (unsigned short*)(ws + 25165824);      // Q,K,V: 3 x 16 MiB
  unsigned short* EmT = (unsigned short*)(ws + 75497472);      // 1 KiB
  unsigned*       MB  = (unsigned*)     (ws + 75499520);       // 1 MiB bit-packed mask
  unsigned short* Vt  = xb;
  unsigned short* AO  = qkv + (size_t)2*8388608;

  cast_f32_bf16<<<4096, 256, 0, stream>>>(x,  xb,            1048576);
  cast_f32_bf16<<<512,  256, 0, stream>>>(Wq, Wb,            131072);
  cast_f32_bf16<<<512,  256, 0, stream>>>(Wk, Wb + 1048576,  131072);
  cast_f32_bf16<<<512,  256, 0, stream>>>(Wv, Wb + 2097152,  131072);
  cast_f32_bf16<<<512,  256, 0, stream>>>(Wo, Wb + 3145728,  131072);
  prep_em<<<1, 256, 0, stream>>>(ent, EmT);
  prep_maskbits<<<1024, 256, 0, stream>>>(msk, MB);

  gemm_bt<0><<<dim3(8,64,3), 256, 0, stream>>>(xb, Wb, bq, bk, bv, (void*)qkv);
  transpose_v<<<4096, 256, 0, stream>>>(qkv + (size_t)2*8388608, Vt);
  attn_fused<<<512, 512, 0, stream>>>(qkv, qkv + 8388608, Vt, MB, EmT, AO);
  gemm_bt<1><<<dim3(8,64,1), 256, 0, stream>>>(AO, Wb + 3145728, bo, bo, bo, d_out);

  (void)in_sizes; (void)n_in; (void)out_size; (void)ws_size;
}